// Round 12
// baseline (425.162 us; speedup 1.0000x reference)
//
#include <hip/hip_runtime.h>

#define N_NODES 100000
#define N_EDGES 640000
#define HID 128
#define N_CLASSES 40
#define N_GRAPHS 128
#define BN_EPS 1e-5f
#define POOL_SLICES 16

#define GEMM_GRID 1563   // (N_NODES + 63) / 64
#define COUNT_GRID 2500  // (N_EDGES + 255) / 256
#define PACK_BLOCKS 64   // 16384 elems / 256 per weight matrix
#define SCAN_BLOCKS 98   // (N_NODES + 1023) / 1024

typedef __attribute__((ext_vector_type(8))) short bf16x8;
typedef __attribute__((ext_vector_type(4))) float f32x4;

// round-to-nearest-even f32 -> bf16 (as raw u16)
__device__ __forceinline__ unsigned short f2bf(float f) {
    unsigned u = __float_as_uint(f);
    u += 0x7FFFu + ((u >> 16) & 1u);
    return (unsigned short)(u >> 16);
}

__device__ __forceinline__ float bflo(unsigned u) { return __uint_as_float(u << 16); }
__device__ __forceinline__ float bfhi(unsigned u) { return __uint_as_float(u & 0xFFFF0000u); }

// ---------------------------------------------------------------------------
// Pack W [128x128 f32, row-major k,n] -> bf16 fragment layout:
// Wb[(k>>3)*1024 + n*8 + (k&7)].
// ---------------------------------------------------------------------------
__global__ void packW(const float* __restrict__ W, unsigned short* __restrict__ Wb) {
    int idx = blockIdx.x * 256 + threadIdx.x;  // 0..16383
    int k = idx >> 7, n = idx & 127;
    Wb[(k >> 3) * 1024 + n * 8 + (k & 7)] = f2bf(W[k * 128 + n]);
}

// ---------------------------------------------------------------------------
// Phase A mega-kernel: [gemm layer-1] || [edge counting + slot capture] ||
// [pack Wb1/Wb2] || [zero bnacc/poolAcc/ticket]. Independent block ranges.
// ---------------------------------------------------------------------------
__global__ __launch_bounds__(256) void phaseA(
    const float* __restrict__ x, const unsigned short* __restrict__ Wb0,
    const int* __restrict__ row, const int* __restrict__ col,
    int* degcnt, int* cnt, int* __restrict__ slot,
    const float* __restrict__ W1, const float* __restrict__ W2,
    unsigned short* __restrict__ Wb1, unsigned short* __restrict__ Wb2,
    unsigned short* __restrict__ outA,
    float* __restrict__ bnacc, float* __restrict__ poolAcc, int* __restrict__ ticket,
    int nRows, int E) {
    const int b = blockIdx.x;

    if (b < GEMM_GRID) {
        // ---- gemm layer 1: outA = bf16( x @ W0 ) ----
        const int wave = threadIdx.x >> 6;
        const int lane = threadIdx.x & 63;
        const int lrow = lane & 15;
        const int lk = lane >> 4;
        const long rowA = (long)b * 64 + wave * 16 + lrow;
        const bool okA = rowA < (long)nRows;
        const float* rp = x + (okA ? rowA : 0) * 128;

        bf16x8 afrag[4];
#pragma unroll
        for (int kk = 0; kk < 4; ++kk) {
            int k0 = kk * 32 + lk * 8;
            float4 v0, v1;
            if (okA) {
                v0 = *(const float4*)(rp + k0);
                v1 = *(const float4*)(rp + k0 + 4);
            } else {
                v0 = v1 = make_float4(0.f, 0.f, 0.f, 0.f);
            }
            bf16x8 a;
            a[0] = (short)f2bf(v0.x); a[1] = (short)f2bf(v0.y);
            a[2] = (short)f2bf(v0.z); a[3] = (short)f2bf(v0.w);
            a[4] = (short)f2bf(v1.x); a[5] = (short)f2bf(v1.y);
            a[6] = (short)f2bf(v1.z); a[7] = (short)f2bf(v1.w);
            afrag[kk] = a;
        }

        f32x4 acc[8];
#pragma unroll
        for (int nt = 0; nt < 8; ++nt) acc[nt] = (f32x4){0.f, 0.f, 0.f, 0.f};

#pragma unroll
        for (int nt = 0; nt < 8; ++nt) {
            const unsigned short* wp = Wb0 + lk * 1024 + (nt * 16 + lrow) * 8;
#pragma unroll
            for (int kk = 0; kk < 4; ++kk) {
                bf16x8 bb = *(const bf16x8*)(wp + kk * 4096);
                acc[nt] = __builtin_amdgcn_mfma_f32_16x16x32_bf16(afrag[kk], bb, acc[nt], 0, 0, 0);
            }
        }

        const long rowD0 = (long)b * 64 + wave * 16 + lk * 4;
#pragma unroll
        for (int r = 0; r < 4; ++r) {
            long rd = rowD0 + r;
            if (rd < nRows) {
                unsigned short* op = outA + rd * 128 + lrow;
#pragma unroll
                for (int nt = 0; nt < 8; ++nt) op[nt * 16] = f2bf(acc[nt][r]);
            }
        }
    } else if (b < GEMM_GRID + COUNT_GRID) {
        // ---- edge degree counting + slot capture ----
        int e = (b - GEMM_GRID) * 256 + threadIdx.x;
        if (e < E) {
            atomicAdd(&degcnt[row[e]], 1);
            slot[e] = atomicAdd(&cnt[col[e]], 1);
        }
    } else if (b < GEMM_GRID + COUNT_GRID + 2 * PACK_BLOCKS) {
        // ---- pack W1 / W2 to bf16 fragment layout ----
        int pb = b - GEMM_GRID - COUNT_GRID;  // 0..127
        const float* Wsrc = (pb < PACK_BLOCKS) ? W1 : W2;
        unsigned short* Wdst = (pb < PACK_BLOCKS) ? Wb1 : Wb2;
        int idx = (pb & (PACK_BLOCKS - 1)) * 256 + threadIdx.x;
        int k = idx >> 7, n = idx & 127;
        Wdst[(k >> 3) * 1024 + n * 8 + (k & 7)] = f2bf(Wsrc[k * 128 + n]);
    } else {
        // ---- zero accumulators (bnacc[256], poolAcc[16384], ticket) ----
        bnacc[threadIdx.x] = 0.f;
        for (int i = threadIdx.x; i < 128 * 128; i += 256) poolAcc[i] = 0.f;
        if (threadIdx.x == 0) *ticket = 0;
    }
}

// ---------------------------------------------------------------------------
// Fused: [scanA: block-local exclusive scan of cnt -> rowptr + blockSums] ||
// [dinv from degcnt]. Independent data -> block-range split.
// ---------------------------------------------------------------------------
__global__ __launch_bounds__(256) void scan_dinv(
    const int* __restrict__ cnt, int* __restrict__ rowptr, int* __restrict__ blockSums,
    const int* __restrict__ degcnt, float* __restrict__ dinv, int n) {
    if (blockIdx.x < SCAN_BLOCKS) {
        __shared__ int sdata[256];
        int t = threadIdx.x;
        int base = blockIdx.x * 1024 + t * 4;
        int c[4];
#pragma unroll
        for (int j = 0; j < 4; ++j) c[j] = (base + j < n) ? cnt[base + j] : 0;
        int s = c[0] + c[1] + c[2] + c[3];
        sdata[t] = s;
        __syncthreads();
        for (int off = 1; off < 256; off <<= 1) {
            int v = (t >= off) ? sdata[t - off] : 0;
            __syncthreads();
            sdata[t] += v;
            __syncthreads();
        }
        int excl = sdata[t] - s;
        if (t == 255) blockSums[blockIdx.x] = sdata[255];
        int run = excl;
#pragma unroll
        for (int j = 0; j < 4; ++j) {
            if (base + j < n) rowptr[base + j] = run;
            run += c[j];
        }
    } else {
        int i = (blockIdx.x - SCAN_BLOCKS) * 256 + threadIdx.x;
        if (i < n) dinv[i] = rsqrtf((float)degcnt[i] + 1.0f);
    }
}

// ---------------------------------------------------------------------------
// Fused scanB+scanC: each block computes its own region offset by reducing
// the blockSums prefix locally (<=98 values), then adds it to rowptr.
// ---------------------------------------------------------------------------
__global__ __launch_bounds__(256) void scan_finish(
    int* __restrict__ rowptr, const int* __restrict__ blockSums, int n, int nb) {
    int r = blockIdx.x >> 2;  // 1024-region index of this block's 256 indices
    __shared__ int sdata[128];
    int t = threadIdx.x;
    if (t < 128) sdata[t] = (t < nb && t < r) ? blockSums[t] : 0;
    __syncthreads();
    for (int off = 64; off > 0; off >>= 1) {
        if (t < off) sdata[t] += sdata[t + off];
        __syncthreads();
    }
    int offv = sdata[0];
    int i = blockIdx.x * 256 + t;
    if (i < n) rowptr[i] += offv;
}

// fill without atomics: position = rowptr[col] + slot captured at count time
__global__ void fill_kernel(const int* __restrict__ row, const int* __restrict__ col,
                            const int* __restrict__ rowptr, const int* __restrict__ slot,
                            int* __restrict__ srcIdx, int E) {
    int e = blockIdx.x * 256 + threadIdx.x;
    if (e < E) srcIdx[rowptr[col[e]] + slot[e]] = row[e];
}

// ---------------------------------------------------------------------------
// MFMA GEMM (layers 2,3): out_bf16 = bf16( relu(BN(in_bf16)) @ W ).
// ---------------------------------------------------------------------------
__global__ __launch_bounds__(256) void gemm_mfma(
    const unsigned short* __restrict__ in, const unsigned short* __restrict__ Wb,
    const float* __restrict__ bn_s, const float* __restrict__ bn_t,
    unsigned short* __restrict__ out, int nRows) {
    const int wave = threadIdx.x >> 6;
    const int lane = threadIdx.x & 63;
    const int lrow = lane & 15;
    const int lk = lane >> 4;
    const long rowA = (long)blockIdx.x * 64 + wave * 16 + lrow;
    const bool okA = rowA < (long)nRows;
    const unsigned short* rp = in + (okA ? rowA : 0) * 128;

    bf16x8 afrag[4];
#pragma unroll
    for (int kk = 0; kk < 4; ++kk) {
        int k0 = kk * 32 + lk * 8;
        unsigned ru[4] = {0u, 0u, 0u, 0u};
        if (okA) {
            uint4 u = *(const uint4*)(rp + k0);
            ru[0] = u.x; ru[1] = u.y; ru[2] = u.z; ru[3] = u.w;
        }
        float f[8];
        f[0] = bflo(ru[0]); f[1] = bfhi(ru[0]);
        f[2] = bflo(ru[1]); f[3] = bfhi(ru[1]);
        f[4] = bflo(ru[2]); f[5] = bfhi(ru[2]);
        f[6] = bflo(ru[3]); f[7] = bfhi(ru[3]);
        float4 s0 = *(const float4*)&bn_s[k0];
        float4 s1 = *(const float4*)&bn_s[k0 + 4];
        float4 t0 = *(const float4*)&bn_t[k0];
        float4 t1 = *(const float4*)&bn_t[k0 + 4];
        f[0] = fmaxf(fmaf(f[0], s0.x, t0.x), 0.f);
        f[1] = fmaxf(fmaf(f[1], s0.y, t0.y), 0.f);
        f[2] = fmaxf(fmaf(f[2], s0.z, t0.z), 0.f);
        f[3] = fmaxf(fmaf(f[3], s0.w, t0.w), 0.f);
        f[4] = fmaxf(fmaf(f[4], s1.x, t1.x), 0.f);
        f[5] = fmaxf(fmaf(f[5], s1.y, t1.y), 0.f);
        f[6] = fmaxf(fmaf(f[6], s1.z, t1.z), 0.f);
        f[7] = fmaxf(fmaf(f[7], s1.w, t1.w), 0.f);
        bf16x8 a;
#pragma unroll
        for (int j = 0; j < 8; ++j) a[j] = (short)f2bf(f[j]);
        afrag[kk] = a;
    }

    f32x4 acc[8];
#pragma unroll
    for (int nt = 0; nt < 8; ++nt) acc[nt] = (f32x4){0.f, 0.f, 0.f, 0.f};

#pragma unroll
    for (int nt = 0; nt < 8; ++nt) {
        const unsigned short* wp = Wb + lk * 1024 + (nt * 16 + lrow) * 8;
#pragma unroll
        for (int kk = 0; kk < 4; ++kk) {
            bf16x8 b = *(const bf16x8*)(wp + kk * 4096);
            acc[nt] = __builtin_amdgcn_mfma_f32_16x16x32_bf16(afrag[kk], b, acc[nt], 0, 0, 0);
        }
    }

    const long rowD0 = (long)blockIdx.x * 64 + wave * 16 + lk * 4;
#pragma unroll
    for (int r = 0; r < 4; ++r) {
        long rd = rowD0 + r;
        if (rd < nRows) {
            unsigned short* op = out + rd * 128 + lrow;
#pragma unroll
            for (int nt = 0; nt < 8; ++nt) op[nt * 16] = f2bf(acc[nt][r]);
        }
    }
}

// ---------------------------------------------------------------------------
// Aggregation: out_bf16[v] = bf16( dinv[v] * sum dinv[src] * h_bf16[src] ).
// Wave per node; lane loads uint4 (8 cols): 16 lanes/row -> one wave-load
// fetches FOUR edges; 4 loads in flight -> 16 edges/chunk.
// ---------------------------------------------------------------------------
__global__ __launch_bounds__(256) void agg_kernel(
    const unsigned short* __restrict__ h, const int* __restrict__ rowptr,
    const int* __restrict__ cnt, const int* __restrict__ srcIdx,
    const float* __restrict__ dinv, unsigned short* __restrict__ out, int nNodes) {
    int wave = threadIdx.x >> 6;
    int lane = threadIdx.x & 63;
    int q = lane >> 4;    // edge sub-slot 0..3
    int c4 = lane & 15;   // cols 8*c4 .. 8*c4+7
    int v = blockIdx.x * 4 + wave;
    if (v >= nNodes) return;
    int start = rowptr[v];
    int n = cnt[v];
    float a0[8], a1[8], a2[8], a3[8];
#pragma unroll
    for (int j = 0; j < 8; ++j) { a0[j] = 0.f; a1[j] = 0.f; a2[j] = 0.f; a3[j] = 0.f; }
    for (int e = 0; e < n; e += 16) {
        int e0 = e + q, e1 = e + 4 + q, e2 = e + 8 + q, e3 = e + 12 + q;
        int i0 = start + ((e0 < n) ? e0 : 0);
        int i1 = start + ((e1 < n) ? e1 : 0);
        int i2 = start + ((e2 < n) ? e2 : 0);
        int i3 = start + ((e3 < n) ? e3 : 0);
        int s0 = srcIdx[i0], s1 = srcIdx[i1], s2 = srcIdx[i2], s3 = srcIdx[i3];
        float w0 = (e0 < n) ? dinv[s0] : 0.f;
        float w1 = (e1 < n) ? dinv[s1] : 0.f;
        float w2 = (e2 < n) ? dinv[s2] : 0.f;
        float w3 = (e3 < n) ? dinv[s3] : 0.f;
        uint4 u0 = *(const uint4*)&h[(long)s0 * 128 + c4 * 8];
        uint4 u1 = *(const uint4*)&h[(long)s1 * 128 + c4 * 8];
        uint4 u2 = *(const uint4*)&h[(long)s2 * 128 + c4 * 8];
        uint4 u3 = *(const uint4*)&h[(long)s3 * 128 + c4 * 8];
        a0[0] = fmaf(w0, bflo(u0.x), a0[0]); a0[1] = fmaf(w0, bfhi(u0.x), a0[1]);
        a0[2] = fmaf(w0, bflo(u0.y), a0[2]); a0[3] = fmaf(w0, bfhi(u0.y), a0[3]);
        a0[4] = fmaf(w0, bflo(u0.z), a0[4]); a0[5] = fmaf(w0, bfhi(u0.z), a0[5]);
        a0[6] = fmaf(w0, bflo(u0.w), a0[6]); a0[7] = fmaf(w0, bfhi(u0.w), a0[7]);
        a1[0] = fmaf(w1, bflo(u1.x), a1[0]); a1[1] = fmaf(w1, bfhi(u1.x), a1[1]);
        a1[2] = fmaf(w1, bflo(u1.y), a1[2]); a1[3] = fmaf(w1, bfhi(u1.y), a1[3]);
        a1[4] = fmaf(w1, bflo(u1.z), a1[4]); a1[5] = fmaf(w1, bfhi(u1.z), a1[5]);
        a1[6] = fmaf(w1, bflo(u1.w), a1[6]); a1[7] = fmaf(w1, bfhi(u1.w), a1[7]);
        a2[0] = fmaf(w2, bflo(u2.x), a2[0]); a2[1] = fmaf(w2, bfhi(u2.x), a2[1]);
        a2[2] = fmaf(w2, bflo(u2.y), a2[2]); a2[3] = fmaf(w2, bfhi(u2.y), a2[3]);
        a2[4] = fmaf(w2, bflo(u2.z), a2[4]); a2[5] = fmaf(w2, bfhi(u2.z), a2[5]);
        a2[6] = fmaf(w2, bflo(u2.w), a2[6]); a2[7] = fmaf(w2, bfhi(u2.w), a2[7]);
        a3[0] = fmaf(w3, bflo(u3.x), a3[0]); a3[1] = fmaf(w3, bfhi(u3.x), a3[1]);
        a3[2] = fmaf(w3, bflo(u3.y), a3[2]); a3[3] = fmaf(w3, bfhi(u3.y), a3[3]);
        a3[4] = fmaf(w3, bflo(u3.z), a3[4]); a3[5] = fmaf(w3, bfhi(u3.z), a3[5]);
        a3[6] = fmaf(w3, bflo(u3.w), a3[6]); a3[7] = fmaf(w3, bfhi(u3.w), a3[7]);
    }
    float r[8];
#pragma unroll
    for (int j = 0; j < 8; ++j) {
        r[j] = (a0[j] + a1[j]) + (a2[j] + a3[j]);
        r[j] += __shfl_xor(r[j], 16);
        r[j] += __shfl_xor(r[j], 32);
    }
    if (q == 0) {
        float dv = dinv[v];
        uint4 o;
        o.x = ((unsigned)f2bf(r[1] * dv) << 16) | (unsigned)f2bf(r[0] * dv);
        o.y = ((unsigned)f2bf(r[3] * dv) << 16) | (unsigned)f2bf(r[2] * dv);
        o.z = ((unsigned)f2bf(r[5] * dv) << 16) | (unsigned)f2bf(r[4] * dv);
        o.w = ((unsigned)f2bf(r[7] * dv) << 16) | (unsigned)f2bf(r[6] * dv);
        *(uint4*)&out[(long)v * 128 + c4 * 8] = o;
    }
}

// ---------------------------------------------------------------------------
// BN statistics + finalize (fused): per-column sum/sumsq via block partials +
// atomics; the LAST block (atomic ticket) computes bn_s/bn_t and re-zeroes
// sums + ticket for the next layer.
// ---------------------------------------------------------------------------
__global__ __launch_bounds__(256) void bnstats_fused(
    const unsigned short* __restrict__ h, float* __restrict__ sums, int nRows,
    const float* __restrict__ gamma, const float* __restrict__ beta,
    float* __restrict__ bn_s, float* __restrict__ bn_t, float invN,
    int* __restrict__ ticket) {
    int c2 = threadIdx.x & 63;
    int rg = threadIdx.x >> 6;
    int chunk = (nRows + gridDim.x - 1) / gridDim.x;
    int r0 = blockIdx.x * chunk;
    int r1 = min(r0 + chunk, nRows);
    float slo = 0.f, s2lo = 0.f, shi = 0.f, s2hi = 0.f;
    for (int r = r0 + rg; r < r1; r += 4) {
        unsigned u = *(const unsigned*)&h[(long)r * 128 + c2 * 2];
        float lo = bflo(u), hi = bfhi(u);
        slo += lo; s2lo = fmaf(lo, lo, s2lo);
        shi += hi; s2hi = fmaf(hi, hi, s2hi);
    }
    __shared__ float l[4][256];
    l[0][threadIdx.x] = slo; l[1][threadIdx.x] = s2lo;
    l[2][threadIdx.x] = shi; l[3][threadIdx.x] = s2hi;
    __syncthreads();
    if (rg == 0) {
        float a = 0.f, b = 0.f, c = 0.f, d = 0.f;
#pragma unroll
        for (int g = 0; g < 4; ++g) {
            a += l[0][g * 64 + c2]; b += l[1][g * 64 + c2];
            c += l[2][g * 64 + c2]; d += l[3][g * 64 + c2];
        }
        atomicAdd(&sums[c2 * 2], a);
        atomicAdd(&sums[128 + c2 * 2], b);
        atomicAdd(&sums[c2 * 2 + 1], c);
        atomicAdd(&sums[129 + c2 * 2], d);
    }
    // last-block-done: finalize BN params
    __threadfence();
    __shared__ int isLast;
    if (threadIdx.x == 0) isLast = (atomicAdd(ticket, 1) == (int)gridDim.x - 1);
    __syncthreads();
    if (isLast) {
        __threadfence();  // acquire all blocks' sums
        int c = threadIdx.x;
        float s_val = 0.f, t_val = 0.f;
        if (c < 128) {
            float mean = sums[c] * invN;
            float var = sums[128 + c] * invN - mean * mean;
            float rs = rsqrtf(var + BN_EPS);
            s_val = gamma[c] * rs;
            t_val = beta[c] - mean * s_val;
        }
        __syncthreads();  // all reads of sums done before re-zero
        if (c < 128) { bn_s[c] = s_val; bn_t[c] = t_val; }
        sums[threadIdx.x] = 0.f;  // re-zero 256 floats for next layer
        if (threadIdx.x == 0) *ticket = 0;
    }
}

// ---------------------------------------------------------------------------
// Global mean pool over bf16 h: per-slice partial sums -> poolAcc (f32).
// ---------------------------------------------------------------------------
__global__ __launch_bounds__(256) void pool_partial(
    const unsigned short* __restrict__ h, const int* __restrict__ batch,
    float* __restrict__ poolAcc, int nNodes) {
    int g = blockIdx.x / POOL_SLICES;
    int s = blockIdx.x % POOL_SLICES;
    int a = 0, b = nNodes;
    while (a < b) { int m = (a + b) >> 1; if (batch[m] < g) a = m + 1; else b = m; }
    int lo = a;
    b = nNodes;
    while (a < b) { int m = (a + b) >> 1; if (batch[m] < g + 1) a = m + 1; else b = m; }
    int hi = a;
    int len = hi - lo;
    int per = (len + POOL_SLICES - 1) / POOL_SLICES;
    int a0 = lo + s * per;
    int a1 = min(a0 + per, hi);
    if (a0 >= a1) return;
    int c2 = threadIdx.x & 63;
    int rg = threadIdx.x >> 6;
    float alo = 0.f, ahi = 0.f;
    for (int v = a0 + rg; v < a1; v += 4) {
        unsigned u = *(const unsigned*)&h[(long)v * 128 + c2 * 2];
        alo += bflo(u);
        ahi += bfhi(u);
    }
    __shared__ float l[2][256];
    l[0][threadIdx.x] = alo;
    l[1][threadIdx.x] = ahi;
    __syncthreads();
    if (rg == 0) {
        float aa = 0.f, bb = 0.f;
#pragma unroll
        for (int gg = 0; gg < 4; ++gg) {
            aa += l[0][gg * 64 + c2];
            bb += l[1][gg * 64 + c2];
        }
        atomicAdd(&poolAcc[g * 128 + c2 * 2], aa);
        atomicAdd(&poolAcc[g * 128 + c2 * 2 + 1], bb);
    }
}

// ---------------------------------------------------------------------------
// MLP head: mean = poolAcc/cnt; relu(xg@Wg1+bg1) @ Wg2 + bg2 -> log_softmax
// ---------------------------------------------------------------------------
__global__ __launch_bounds__(128) void head_kernel(
    const float* __restrict__ poolAcc, const int* __restrict__ batch,
    const float* __restrict__ Wg1, const float* __restrict__ bg1,
    const float* __restrict__ Wg2, const float* __restrict__ bg2,
    float* __restrict__ out, int nNodes) {
    __shared__ float xr[128], tr[128], lg[N_CLASSES], red[2];
    int g = blockIdx.x, t = threadIdx.x;
    int a = 0, b = nNodes;
    while (a < b) { int m = (a + b) >> 1; if (batch[m] < g) a = m + 1; else b = m; }
    int lo = a;
    b = nNodes;
    while (a < b) { int m = (a + b) >> 1; if (batch[m] < g + 1) a = m + 1; else b = m; }
    float cntf = fmaxf((float)(a - lo), 1.0f);
    xr[t] = poolAcc[g * 128 + t] / cntf;
    __syncthreads();
    float s = bg1[t];
    for (int k = 0; k < 128; ++k) s = fmaf(xr[k], Wg1[k * 128 + t], s);
    tr[t] = fmaxf(s, 0.f);
    __syncthreads();
    if (t < N_CLASSES) {
        float s2 = bg2[t];
        for (int k = 0; k < 128; ++k) s2 = fmaf(tr[k], Wg2[k * N_CLASSES + t], s2);
        lg[t] = s2;
    }
    __syncthreads();
    if (t == 0) {
        float m = -1e30f;
        for (int j = 0; j < N_CLASSES; ++j) m = fmaxf(m, lg[j]);
        float se = 0.f;
        for (int j = 0; j < N_CLASSES; ++j) se += expf(lg[j] - m);
        red[0] = m;
        red[1] = logf(se);
    }
    __syncthreads();
    if (t < N_CLASSES) out[g * N_CLASSES + t] = lg[t] - red[0] - red[1];
}

// ---------------------------------------------------------------------------
extern "C" void kernel_launch(void* const* d_in, const int* in_sizes, int n_in,
                              void* d_out, int out_size, void* d_ws, size_t ws_size,
                              hipStream_t stream) {
    const float* x = (const float*)d_in[0];
    const int* edge = (const int*)d_in[1];
    const int* row = edge;
    const int* col = edge + N_EDGES;
    const int* batch = (const int*)d_in[2];
    const float* W0 = (const float*)d_in[3];
    const float* g0 = (const float*)d_in[4];
    const float* b0 = (const float*)d_in[5];
    const float* W1 = (const float*)d_in[6];
    const float* g1 = (const float*)d_in[7];
    const float* b1 = (const float*)d_in[8];
    const float* W2 = (const float*)d_in[9];
    const float* Wg1 = (const float*)d_in[10];
    const float* bg1 = (const float*)d_in[11];
    const float* Wg2 = (const float*)d_in[12];
    const float* bg2 = (const float*)d_in[13];
    float* out = (float*)d_out;

    char* p = (char*)d_ws;
    auto alloc = [&](size_t bytes) {
        void* r = (void*)p;
        p += (bytes + 255) & ~(size_t)255;
        return r;
    };
    unsigned short* bufA = (unsigned short*)alloc((size_t)N_NODES * 128 * 2);  // bf16 gemm out
    unsigned short* bufB = (unsigned short*)alloc((size_t)N_NODES * 128 * 2);  // bf16 agg out
    float* dinv = (float*)alloc((size_t)N_NODES * 4);
    int* counts = (int*)alloc((size_t)2 * N_NODES * 4);  // degcnt | cnt contiguous
    int* degcnt = counts;
    int* cnt = counts + N_NODES;
    int* rowptr = (int*)alloc((size_t)N_NODES * 4);
    int* slot = (int*)alloc((size_t)N_EDGES * 4);
    int* srcIdx = (int*)alloc((size_t)N_EDGES * 4);
    int* blockSums = (int*)alloc(1024 * 4);
    float* bnacc = (float*)alloc(256 * 4);
    float* bn_s = (float*)alloc(128 * 4);
    float* bn_t = (float*)alloc(128 * 4);
    float* poolAcc = (float*)alloc(128 * 128 * 4);
    int* ticket = (int*)alloc(256);
    unsigned short* Wb0 = (unsigned short*)alloc(128 * 128 * 2);
    unsigned short* Wb1 = (unsigned short*)alloc(128 * 128 * 2);
    unsigned short* Wb2 = (unsigned short*)alloc(128 * 128 * 2);

    const int E = N_EDGES, N = N_NODES;

    // 1: zero both count arrays in one memset (contiguous)
    hipMemsetAsync(counts, 0, (size_t)2 * N * 4, stream);
    // 2: pack W0 (needed by phaseA's gemm branch)
    packW<<<PACK_BLOCKS, 256, 0, stream>>>(W0, Wb0);
    // 3: phase A: gemm1 || count+slot || pack W1/W2 || zero accumulators
    phaseA<<<GEMM_GRID + COUNT_GRID + 2 * PACK_BLOCKS + 1, 256, 0, stream>>>(
        x, Wb0, row, col, degcnt, cnt, slot, W1, W2, Wb1, Wb2, bufA,
        bnacc, poolAcc, ticket, N, E);
    // 4: scanA || dinv
    scan_dinv<<<SCAN_BLOCKS + (N + 255) / 256, 256, 0, stream>>>(
        cnt, rowptr, blockSums, degcnt, dinv, N);
    // 5: scanB+scanC fused
    scan_finish<<<(N + 255) / 256, 256, 0, stream>>>(rowptr, blockSums, N, SCAN_BLOCKS);
    // 6: fill (no atomics)
    fill_kernel<<<(E + 255) / 256, 256, 0, stream>>>(row, col, rowptr, slot, srcIdx, E);

    const int gemmGrid = (N + 63) / 64;  // 1563
    const int aggGrid = (N + 3) / 4;     // 25000

    // 7-8: layer 1 agg + BN (stats+finalize fused)
    agg_kernel<<<aggGrid, 256, 0, stream>>>(bufA, rowptr, cnt, srcIdx, dinv, bufB, N);
    bnstats_fused<<<512, 256, 0, stream>>>(bufB, bnacc, N, g0, b0, bn_s, bn_t, 1.0f / N, ticket);

    // 9-11: layer 2
    gemm_mfma<<<gemmGrid, 256, 0, stream>>>(bufB, Wb1, bn_s, bn_t, bufA, N);
    agg_kernel<<<aggGrid, 256, 0, stream>>>(bufA, rowptr, cnt, srcIdx, dinv, bufB, N);
    bnstats_fused<<<512, 256, 0, stream>>>(bufB, bnacc, N, g1, b1, bn_s, bn_t, 1.0f / N, ticket);

    // 12-13: layer 3
    gemm_mfma<<<gemmGrid, 256, 0, stream>>>(bufB, Wb2, bn_s, bn_t, bufA, N);
    agg_kernel<<<aggGrid, 256, 0, stream>>>(bufA, rowptr, cnt, srcIdx, dinv, bufB, N);

    // 14-15: pool + head
    pool_partial<<<N_GRAPHS * POOL_SLICES, 256, 0, stream>>>(bufB, batch, poolAcc, N);
    head_kernel<<<N_GRAPHS, 128, 0, stream>>>(poolAcc, batch, Wg1, bg1, Wg2, bg2, out, N);
}

// Round 13
// 406.331 us; speedup vs baseline: 1.0463x; 1.0463x over previous
//
#include <hip/hip_runtime.h>

#define N_NODES 100000
#define N_EDGES 640000
#define HID 128
#define N_CLASSES 40
#define N_GRAPHS 128
#define BN_EPS 1e-5f
#define POOL_SLICES 16

#define GEMM_GRID 1563   // (N_NODES + 63) / 64
#define COUNT_GRID 2500  // (N_EDGES + 255) / 256
#define PACK_BLOCKS 64   // 16384 elems / 256 per weight matrix

typedef __attribute__((ext_vector_type(8))) short bf16x8;
typedef __attribute__((ext_vector_type(4))) float f32x4;

// round-to-nearest-even f32 -> bf16 (as raw u16)
__device__ __forceinline__ unsigned short f2bf(float f) {
    unsigned u = __float_as_uint(f);
    u += 0x7FFFu + ((u >> 16) & 1u);
    return (unsigned short)(u >> 16);
}

__device__ __forceinline__ float bflo(unsigned u) { return __uint_as_float(u << 16); }
__device__ __forceinline__ float bfhi(unsigned u) { return __uint_as_float(u & 0xFFFF0000u); }

// ---------------------------------------------------------------------------
// Pack W [128x128 f32, row-major k,n] -> bf16 fragment layout:
// Wb[(k>>3)*1024 + n*8 + (k&7)].
// ---------------------------------------------------------------------------
__global__ void packW(const float* __restrict__ W, unsigned short* __restrict__ Wb) {
    int idx = blockIdx.x * 256 + threadIdx.x;  // 0..16383
    int k = idx >> 7, n = idx & 127;
    Wb[(k >> 3) * 1024 + n * 8 + (k & 7)] = f2bf(W[k * 128 + n]);
}

// ---------------------------------------------------------------------------
// Phase A mega-kernel: [gemm layer-1] || [edge counting + slot capture] ||
// [pack Wb1/Wb2]. count branch records each edge's arrival order (slot) so
// the later fill pass needs NO atomics.
// ---------------------------------------------------------------------------
__global__ __launch_bounds__(256) void phaseA(
    const float* __restrict__ x, const unsigned short* __restrict__ Wb0,
    const int* __restrict__ row, const int* __restrict__ col,
    int* degcnt, int* cnt, int* __restrict__ slot,
    const float* __restrict__ W1, const float* __restrict__ W2,
    unsigned short* __restrict__ Wb1, unsigned short* __restrict__ Wb2,
    unsigned short* __restrict__ outA, int nRows, int E) {
    const int b = blockIdx.x;

    if (b < GEMM_GRID) {
        // ---- gemm layer 1: outA = bf16( x @ W0 ) ----
        const int wave = threadIdx.x >> 6;
        const int lane = threadIdx.x & 63;
        const int lrow = lane & 15;
        const int lk = lane >> 4;
        const long rowA = (long)b * 64 + wave * 16 + lrow;
        const bool okA = rowA < (long)nRows;
        const float* rp = x + (okA ? rowA : 0) * 128;

        bf16x8 afrag[4];
#pragma unroll
        for (int kk = 0; kk < 4; ++kk) {
            int k0 = kk * 32 + lk * 8;
            float4 v0, v1;
            if (okA) {
                v0 = *(const float4*)(rp + k0);
                v1 = *(const float4*)(rp + k0 + 4);
            } else {
                v0 = v1 = make_float4(0.f, 0.f, 0.f, 0.f);
            }
            bf16x8 a;
            a[0] = (short)f2bf(v0.x); a[1] = (short)f2bf(v0.y);
            a[2] = (short)f2bf(v0.z); a[3] = (short)f2bf(v0.w);
            a[4] = (short)f2bf(v1.x); a[5] = (short)f2bf(v1.y);
            a[6] = (short)f2bf(v1.z); a[7] = (short)f2bf(v1.w);
            afrag[kk] = a;
        }

        f32x4 acc[8];
#pragma unroll
        for (int nt = 0; nt < 8; ++nt) acc[nt] = (f32x4){0.f, 0.f, 0.f, 0.f};

#pragma unroll
        for (int nt = 0; nt < 8; ++nt) {
            const unsigned short* wp = Wb0 + lk * 1024 + (nt * 16 + lrow) * 8;
#pragma unroll
            for (int kk = 0; kk < 4; ++kk) {
                bf16x8 bb = *(const bf16x8*)(wp + kk * 4096);
                acc[nt] = __builtin_amdgcn_mfma_f32_16x16x32_bf16(afrag[kk], bb, acc[nt], 0, 0, 0);
            }
        }

        const long rowD0 = (long)b * 64 + wave * 16 + lk * 4;
#pragma unroll
        for (int r = 0; r < 4; ++r) {
            long rd = rowD0 + r;
            if (rd < nRows) {
                unsigned short* op = outA + rd * 128 + lrow;
#pragma unroll
                for (int nt = 0; nt < 8; ++nt) op[nt * 16] = f2bf(acc[nt][r]);
            }
        }
    } else if (b < GEMM_GRID + COUNT_GRID) {
        // ---- edge degree counting + slot capture ----
        int e = (b - GEMM_GRID) * 256 + threadIdx.x;
        if (e < E) {
            atomicAdd(&degcnt[row[e]], 1);
            slot[e] = atomicAdd(&cnt[col[e]], 1);
        }
    } else {
        // ---- pack W1 / W2 to bf16 fragment layout ----
        int pb = b - GEMM_GRID - COUNT_GRID;  // 0..127
        const float* Wsrc = (pb < PACK_BLOCKS) ? W1 : W2;
        unsigned short* Wdst = (pb < PACK_BLOCKS) ? Wb1 : Wb2;
        int idx = (pb & (PACK_BLOCKS - 1)) * 256 + threadIdx.x;
        int k = idx >> 7, n = idx & 127;
        Wdst[(k >> 3) * 1024 + n * 8 + (k & 7)] = f2bf(Wsrc[k * 128 + n]);
    }
}

__global__ void dinv_kernel(const int* __restrict__ degcnt, float* __restrict__ dinv, int n) {
    int i = blockIdx.x * 256 + threadIdx.x;
    if (i < n) dinv[i] = rsqrtf((float)degcnt[i] + 1.0f);
}

// block-level exclusive scan (1024 elements per block of 256 threads)
__global__ __launch_bounds__(256) void scanA(const int* __restrict__ cnt, int* __restrict__ rowptr,
                                             int* __restrict__ blockSums, int n) {
    __shared__ int sdata[256];
    int t = threadIdx.x;
    int base = blockIdx.x * 1024 + t * 4;
    int c[4];
#pragma unroll
    for (int j = 0; j < 4; ++j) c[j] = (base + j < n) ? cnt[base + j] : 0;
    int s = c[0] + c[1] + c[2] + c[3];
    sdata[t] = s;
    __syncthreads();
    for (int off = 1; off < 256; off <<= 1) {
        int v = (t >= off) ? sdata[t - off] : 0;
        __syncthreads();
        sdata[t] += v;
        __syncthreads();
    }
    int excl = sdata[t] - s;
    if (t == 255) blockSums[blockIdx.x] = sdata[255];
    int run = excl;
#pragma unroll
    for (int j = 0; j < 4; ++j) {
        if (base + j < n) rowptr[base + j] = run;
        run += c[j];
    }
}

__global__ void scanB(const int* __restrict__ blockSums, int* __restrict__ blockOffs, int nb) {
    __shared__ int sdata[128];
    int t = threadIdx.x;
    int v = (t < nb) ? blockSums[t] : 0;
    sdata[t] = v;
    __syncthreads();
    for (int off = 1; off < 128; off <<= 1) {
        int u = (t >= off) ? sdata[t - off] : 0;
        __syncthreads();
        sdata[t] += u;
        __syncthreads();
    }
    if (t < nb) blockOffs[t] = sdata[t] - v;
}

__global__ void scanC(int* __restrict__ rowptr, const int* __restrict__ blockOffs, int n) {
    int i = blockIdx.x * 256 + threadIdx.x;
    if (i < n) rowptr[i] += blockOffs[i >> 10];
}

// fill without atomics: position = rowptr[col] + slot captured at count time
__global__ void fill_kernel(const int* __restrict__ row, const int* __restrict__ col,
                            const int* __restrict__ rowptr, const int* __restrict__ slot,
                            int* __restrict__ srcIdx, int E) {
    int e = blockIdx.x * 256 + threadIdx.x;
    if (e < E) srcIdx[rowptr[col[e]] + slot[e]] = row[e];
}

// ---------------------------------------------------------------------------
// MFMA GEMM (layers 2,3): out_bf16 = bf16( relu(BN(in_bf16)) @ W ).
// ---------------------------------------------------------------------------
__global__ __launch_bounds__(256) void gemm_mfma(
    const unsigned short* __restrict__ in, const unsigned short* __restrict__ Wb,
    const float* __restrict__ bn_s, const float* __restrict__ bn_t,
    unsigned short* __restrict__ out, int nRows) {
    const int wave = threadIdx.x >> 6;
    const int lane = threadIdx.x & 63;
    const int lrow = lane & 15;
    const int lk = lane >> 4;
    const long rowA = (long)blockIdx.x * 64 + wave * 16 + lrow;
    const bool okA = rowA < (long)nRows;
    const unsigned short* rp = in + (okA ? rowA : 0) * 128;

    bf16x8 afrag[4];
#pragma unroll
    for (int kk = 0; kk < 4; ++kk) {
        int k0 = kk * 32 + lk * 8;
        unsigned ru[4] = {0u, 0u, 0u, 0u};
        if (okA) {
            uint4 u = *(const uint4*)(rp + k0);
            ru[0] = u.x; ru[1] = u.y; ru[2] = u.z; ru[3] = u.w;
        }
        float f[8];
        f[0] = bflo(ru[0]); f[1] = bfhi(ru[0]);
        f[2] = bflo(ru[1]); f[3] = bfhi(ru[1]);
        f[4] = bflo(ru[2]); f[5] = bfhi(ru[2]);
        f[6] = bflo(ru[3]); f[7] = bfhi(ru[3]);
        float4 s0 = *(const float4*)&bn_s[k0];
        float4 s1 = *(const float4*)&bn_s[k0 + 4];
        float4 t0 = *(const float4*)&bn_t[k0];
        float4 t1 = *(const float4*)&bn_t[k0 + 4];
        f[0] = fmaxf(fmaf(f[0], s0.x, t0.x), 0.f);
        f[1] = fmaxf(fmaf(f[1], s0.y, t0.y), 0.f);
        f[2] = fmaxf(fmaf(f[2], s0.z, t0.z), 0.f);
        f[3] = fmaxf(fmaf(f[3], s0.w, t0.w), 0.f);
        f[4] = fmaxf(fmaf(f[4], s1.x, t1.x), 0.f);
        f[5] = fmaxf(fmaf(f[5], s1.y, t1.y), 0.f);
        f[6] = fmaxf(fmaf(f[6], s1.z, t1.z), 0.f);
        f[7] = fmaxf(fmaf(f[7], s1.w, t1.w), 0.f);
        bf16x8 a;
#pragma unroll
        for (int j = 0; j < 8; ++j) a[j] = (short)f2bf(f[j]);
        afrag[kk] = a;
    }

    f32x4 acc[8];
#pragma unroll
    for (int nt = 0; nt < 8; ++nt) acc[nt] = (f32x4){0.f, 0.f, 0.f, 0.f};

#pragma unroll
    for (int nt = 0; nt < 8; ++nt) {
        const unsigned short* wp = Wb + lk * 1024 + (nt * 16 + lrow) * 8;
#pragma unroll
        for (int kk = 0; kk < 4; ++kk) {
            bf16x8 b = *(const bf16x8*)(wp + kk * 4096);
            acc[nt] = __builtin_amdgcn_mfma_f32_16x16x32_bf16(afrag[kk], b, acc[nt], 0, 0, 0);
        }
    }

    const long rowD0 = (long)blockIdx.x * 64 + wave * 16 + lk * 4;
#pragma unroll
    for (int r = 0; r < 4; ++r) {
        long rd = rowD0 + r;
        if (rd < nRows) {
            unsigned short* op = out + rd * 128 + lrow;
#pragma unroll
            for (int nt = 0; nt < 8; ++nt) op[nt * 16] = f2bf(acc[nt][r]);
        }
    }
}

// ---------------------------------------------------------------------------
// Aggregation: out_bf16[v] = bf16( dinv[v] * sum dinv[src] * h_bf16[src] ).
// Wave per node; lane loads uint4 (8 cols, 16B): 16 lanes cover a row, so one
// wave-load fetches FOUR edge rows (quarter q serves edge e+q). 4 loads in
// flight -> 16 edges per chunk; deg<=16 nodes finish in ONE latency chain.
// Reduce: slot-sum in regs, shfl_xor(16), shfl_xor(32); q==0 writes uint4.
// ---------------------------------------------------------------------------
__global__ __launch_bounds__(256) void agg_kernel(
    const unsigned short* __restrict__ h, const int* __restrict__ rowptr,
    const int* __restrict__ cnt, const int* __restrict__ srcIdx,
    const float* __restrict__ dinv, unsigned short* __restrict__ out, int nNodes) {
    int wave = threadIdx.x >> 6;
    int lane = threadIdx.x & 63;
    int q = lane >> 4;    // edge sub-slot 0..3
    int c4 = lane & 15;   // cols 8*c4 .. 8*c4+7
    int v = blockIdx.x * 4 + wave;
    if (v >= nNodes) return;
    int start = rowptr[v];
    int n = cnt[v];
    float a0[8], a1[8], a2[8], a3[8];
#pragma unroll
    for (int j = 0; j < 8; ++j) { a0[j] = 0.f; a1[j] = 0.f; a2[j] = 0.f; a3[j] = 0.f; }
    for (int e = 0; e < n; e += 16) {
        int e0 = e + q, e1 = e + 4 + q, e2 = e + 8 + q, e3 = e + 12 + q;
        int i0 = start + ((e0 < n) ? e0 : 0);
        int i1 = start + ((e1 < n) ? e1 : 0);
        int i2 = start + ((e2 < n) ? e2 : 0);
        int i3 = start + ((e3 < n) ? e3 : 0);
        int s0 = srcIdx[i0], s1 = srcIdx[i1], s2 = srcIdx[i2], s3 = srcIdx[i3];
        float w0 = (e0 < n) ? dinv[s0] : 0.f;
        float w1 = (e1 < n) ? dinv[s1] : 0.f;
        float w2 = (e2 < n) ? dinv[s2] : 0.f;
        float w3 = (e3 < n) ? dinv[s3] : 0.f;
        uint4 u0 = *(const uint4*)&h[(long)s0 * 128 + c4 * 8];
        uint4 u1 = *(const uint4*)&h[(long)s1 * 128 + c4 * 8];
        uint4 u2 = *(const uint4*)&h[(long)s2 * 128 + c4 * 8];
        uint4 u3 = *(const uint4*)&h[(long)s3 * 128 + c4 * 8];
        a0[0] = fmaf(w0, bflo(u0.x), a0[0]); a0[1] = fmaf(w0, bfhi(u0.x), a0[1]);
        a0[2] = fmaf(w0, bflo(u0.y), a0[2]); a0[3] = fmaf(w0, bfhi(u0.y), a0[3]);
        a0[4] = fmaf(w0, bflo(u0.z), a0[4]); a0[5] = fmaf(w0, bfhi(u0.z), a0[5]);
        a0[6] = fmaf(w0, bflo(u0.w), a0[6]); a0[7] = fmaf(w0, bfhi(u0.w), a0[7]);
        a1[0] = fmaf(w1, bflo(u1.x), a1[0]); a1[1] = fmaf(w1, bfhi(u1.x), a1[1]);
        a1[2] = fmaf(w1, bflo(u1.y), a1[2]); a1[3] = fmaf(w1, bfhi(u1.y), a1[3]);
        a1[4] = fmaf(w1, bflo(u1.z), a1[4]); a1[5] = fmaf(w1, bfhi(u1.z), a1[5]);
        a1[6] = fmaf(w1, bflo(u1.w), a1[6]); a1[7] = fmaf(w1, bfhi(u1.w), a1[7]);
        a2[0] = fmaf(w2, bflo(u2.x), a2[0]); a2[1] = fmaf(w2, bfhi(u2.x), a2[1]);
        a2[2] = fmaf(w2, bflo(u2.y), a2[2]); a2[3] = fmaf(w2, bfhi(u2.y), a2[3]);
        a2[4] = fmaf(w2, bflo(u2.z), a2[4]); a2[5] = fmaf(w2, bfhi(u2.z), a2[5]);
        a2[6] = fmaf(w2, bflo(u2.w), a2[6]); a2[7] = fmaf(w2, bfhi(u2.w), a2[7]);
        a3[0] = fmaf(w3, bflo(u3.x), a3[0]); a3[1] = fmaf(w3, bfhi(u3.x), a3[1]);
        a3[2] = fmaf(w3, bflo(u3.y), a3[2]); a3[3] = fmaf(w3, bfhi(u3.y), a3[3]);
        a3[4] = fmaf(w3, bflo(u3.z), a3[4]); a3[5] = fmaf(w3, bfhi(u3.z), a3[5]);
        a3[6] = fmaf(w3, bflo(u3.w), a3[6]); a3[7] = fmaf(w3, bfhi(u3.w), a3[7]);
    }
    float r[8];
#pragma unroll
    for (int j = 0; j < 8; ++j) {
        r[j] = (a0[j] + a1[j]) + (a2[j] + a3[j]);
        r[j] += __shfl_xor(r[j], 16);
        r[j] += __shfl_xor(r[j], 32);
    }
    if (q == 0) {
        float dv = dinv[v];
        uint4 o;
        o.x = ((unsigned)f2bf(r[1] * dv) << 16) | (unsigned)f2bf(r[0] * dv);
        o.y = ((unsigned)f2bf(r[3] * dv) << 16) | (unsigned)f2bf(r[2] * dv);
        o.z = ((unsigned)f2bf(r[5] * dv) << 16) | (unsigned)f2bf(r[4] * dv);
        o.w = ((unsigned)f2bf(r[7] * dv) << 16) | (unsigned)f2bf(r[6] * dv);
        *(uint4*)&out[(long)v * 128 + c4 * 8] = o;
    }
}

// ---------------------------------------------------------------------------
// BN statistics over bf16 h: per-column sum and sum-of-squares.
// ---------------------------------------------------------------------------
__global__ __launch_bounds__(256) void bnstats(const unsigned short* __restrict__ h,
                                               float* __restrict__ sums, int nRows) {
    int c2 = threadIdx.x & 63;
    int rg = threadIdx.x >> 6;
    int chunk = (nRows + gridDim.x - 1) / gridDim.x;
    int r0 = blockIdx.x * chunk;
    int r1 = min(r0 + chunk, nRows);
    float slo = 0.f, s2lo = 0.f, shi = 0.f, s2hi = 0.f;
    for (int r = r0 + rg; r < r1; r += 4) {
        unsigned u = *(const unsigned*)&h[(long)r * 128 + c2 * 2];
        float lo = bflo(u), hi = bfhi(u);
        slo += lo; s2lo = fmaf(lo, lo, s2lo);
        shi += hi; s2hi = fmaf(hi, hi, s2hi);
    }
    __shared__ float l[4][256];
    l[0][threadIdx.x] = slo; l[1][threadIdx.x] = s2lo;
    l[2][threadIdx.x] = shi; l[3][threadIdx.x] = s2hi;
    __syncthreads();
    if (rg == 0) {
        float a = 0.f, b = 0.f, c = 0.f, d = 0.f;
#pragma unroll
        for (int g = 0; g < 4; ++g) {
            a += l[0][g * 64 + c2]; b += l[1][g * 64 + c2];
            c += l[2][g * 64 + c2]; d += l[3][g * 64 + c2];
        }
        atomicAdd(&sums[c2 * 2], a);
        atomicAdd(&sums[128 + c2 * 2], b);
        atomicAdd(&sums[c2 * 2 + 1], c);
        atomicAdd(&sums[129 + c2 * 2], d);
    }
}

__global__ void bnfin(const float* __restrict__ sums, const float* __restrict__ gamma,
                      const float* __restrict__ beta, float* __restrict__ bn_s,
                      float* __restrict__ bn_t, float invN) {
    int c = threadIdx.x;
    float mean = sums[c] * invN;
    float var = sums[128 + c] * invN - mean * mean;
    float rs = rsqrtf(var + BN_EPS);
    float s = gamma[c] * rs;
    bn_s[c] = s;
    bn_t[c] = beta[c] - mean * s;
}

// ---------------------------------------------------------------------------
// Global mean pool over bf16 h: per-slice partial sums -> poolAcc (f32).
// ---------------------------------------------------------------------------
__global__ __launch_bounds__(256) void pool_partial(
    const unsigned short* __restrict__ h, const int* __restrict__ batch,
    float* __restrict__ poolAcc, int nNodes) {
    int g = blockIdx.x / POOL_SLICES;
    int s = blockIdx.x % POOL_SLICES;
    int a = 0, b = nNodes;
    while (a < b) { int m = (a + b) >> 1; if (batch[m] < g) a = m + 1; else b = m; }
    int lo = a;
    b = nNodes;
    while (a < b) { int m = (a + b) >> 1; if (batch[m] < g + 1) a = m + 1; else b = m; }
    int hi = a;
    int len = hi - lo;
    int per = (len + POOL_SLICES - 1) / POOL_SLICES;
    int a0 = lo + s * per;
    int a1 = min(a0 + per, hi);
    if (a0 >= a1) return;
    int c2 = threadIdx.x & 63;
    int rg = threadIdx.x >> 6;
    float alo = 0.f, ahi = 0.f;
    for (int v = a0 + rg; v < a1; v += 4) {
        unsigned u = *(const unsigned*)&h[(long)v * 128 + c2 * 2];
        alo += bflo(u);
        ahi += bfhi(u);
    }
    __shared__ float l[2][256];
    l[0][threadIdx.x] = alo;
    l[1][threadIdx.x] = ahi;
    __syncthreads();
    if (rg == 0) {
        float aa = 0.f, bb = 0.f;
#pragma unroll
        for (int gg = 0; gg < 4; ++gg) {
            aa += l[0][gg * 64 + c2];
            bb += l[1][gg * 64 + c2];
        }
        atomicAdd(&poolAcc[g * 128 + c2 * 2], aa);
        atomicAdd(&poolAcc[g * 128 + c2 * 2 + 1], bb);
    }
}

// ---------------------------------------------------------------------------
// MLP head: mean = poolAcc/cnt; relu(xg@Wg1+bg1) @ Wg2 + bg2 -> log_softmax
// ---------------------------------------------------------------------------
__global__ __launch_bounds__(128) void head_kernel(
    const float* __restrict__ poolAcc, const int* __restrict__ batch,
    const float* __restrict__ Wg1, const float* __restrict__ bg1,
    const float* __restrict__ Wg2, const float* __restrict__ bg2,
    float* __restrict__ out, int nNodes) {
    __shared__ float xr[128], tr[128], lg[N_CLASSES], red[2];
    int g = blockIdx.x, t = threadIdx.x;
    int a = 0, b = nNodes;
    while (a < b) { int m = (a + b) >> 1; if (batch[m] < g) a = m + 1; else b = m; }
    int lo = a;
    b = nNodes;
    while (a < b) { int m = (a + b) >> 1; if (batch[m] < g + 1) a = m + 1; else b = m; }
    float cntf = fmaxf((float)(a - lo), 1.0f);
    xr[t] = poolAcc[g * 128 + t] / cntf;
    __syncthreads();
    float s = bg1[t];
    for (int k = 0; k < 128; ++k) s = fmaf(xr[k], Wg1[k * 128 + t], s);
    tr[t] = fmaxf(s, 0.f);
    __syncthreads();
    if (t < N_CLASSES) {
        float s2 = bg2[t];
        for (int k = 0; k < 128; ++k) s2 = fmaf(tr[k], Wg2[k * N_CLASSES + t], s2);
        lg[t] = s2;
    }
    __syncthreads();
    if (t == 0) {
        float m = -1e30f;
        for (int j = 0; j < N_CLASSES; ++j) m = fmaxf(m, lg[j]);
        float se = 0.f;
        for (int j = 0; j < N_CLASSES; ++j) se += expf(lg[j] - m);
        red[0] = m;
        red[1] = logf(se);
    }
    __syncthreads();
    if (t < N_CLASSES) out[g * N_CLASSES + t] = lg[t] - red[0] - red[1];
}

// ---------------------------------------------------------------------------
extern "C" void kernel_launch(void* const* d_in, const int* in_sizes, int n_in,
                              void* d_out, int out_size, void* d_ws, size_t ws_size,
                              hipStream_t stream) {
    const float* x = (const float*)d_in[0];
    const int* edge = (const int*)d_in[1];
    const int* row = edge;
    const int* col = edge + N_EDGES;
    const int* batch = (const int*)d_in[2];
    const float* W0 = (const float*)d_in[3];
    const float* g0 = (const float*)d_in[4];
    const float* b0 = (const float*)d_in[5];
    const float* W1 = (const float*)d_in[6];
    const float* g1 = (const float*)d_in[7];
    const float* b1 = (const float*)d_in[8];
    const float* W2 = (const float*)d_in[9];
    const float* Wg1 = (const float*)d_in[10];
    const float* bg1 = (const float*)d_in[11];
    const float* Wg2 = (const float*)d_in[12];
    const float* bg2 = (const float*)d_in[13];
    float* out = (float*)d_out;

    char* p = (char*)d_ws;
    auto alloc = [&](size_t bytes) {
        void* r = (void*)p;
        p += (bytes + 255) & ~(size_t)255;
        return r;
    };
    unsigned short* bufA = (unsigned short*)alloc((size_t)N_NODES * 128 * 2);  // bf16 gemm out
    unsigned short* bufB = (unsigned short*)alloc((size_t)N_NODES * 128 * 2);  // bf16 agg out
    float* dinv = (float*)alloc((size_t)N_NODES * 4);
    int* degcnt = (int*)alloc((size_t)N_NODES * 4);
    int* cnt = (int*)alloc((size_t)N_NODES * 4);
    int* rowptr = (int*)alloc((size_t)N_NODES * 4);
    int* slot = (int*)alloc((size_t)N_EDGES * 4);
    int* srcIdx = (int*)alloc((size_t)N_EDGES * 4);
    int* blockSums = (int*)alloc(1024 * 4);
    int* blockOffs = (int*)alloc(1024 * 4);
    float* bnacc = (float*)alloc(256 * 4);
    float* bn_s = (float*)alloc(128 * 4);
    float* bn_t = (float*)alloc(128 * 4);
    float* poolAcc = (float*)alloc(128 * 128 * 4);
    unsigned short* Wb0 = (unsigned short*)alloc(128 * 128 * 2);
    unsigned short* Wb1 = (unsigned short*)alloc(128 * 128 * 2);
    unsigned short* Wb2 = (unsigned short*)alloc(128 * 128 * 2);

    const int E = N_EDGES, N = N_NODES;
    const int scanBlocks = (N + 1023) / 1024;  // 98

    // --- zero counters + pack Wb0, then phase A: gemm1 || count+slot || packW1/2
    hipMemsetAsync(degcnt, 0, (size_t)N * 4, stream);
    hipMemsetAsync(cnt, 0, (size_t)N * 4, stream);
    packW<<<PACK_BLOCKS, 256, 0, stream>>>(W0, Wb0);
    phaseA<<<GEMM_GRID + COUNT_GRID + 2 * PACK_BLOCKS, 256, 0, stream>>>(
        x, Wb0, row, col, degcnt, cnt, slot, W1, W2, Wb1, Wb2, bufA, N, E);

    // --- CSR finish (fill has no atomics) ---
    dinv_kernel<<<(N + 255) / 256, 256, 0, stream>>>(degcnt, dinv, N);
    scanA<<<scanBlocks, 256, 0, stream>>>(cnt, rowptr, blockSums, N);
    scanB<<<1, 128, 0, stream>>>(blockSums, blockOffs, scanBlocks);
    scanC<<<(N + 255) / 256, 256, 0, stream>>>(rowptr, blockOffs, N);
    fill_kernel<<<(E + 255) / 256, 256, 0, stream>>>(row, col, rowptr, slot, srcIdx, E);

    const int gemmGrid = (N + 63) / 64;  // 1563
    const int aggGrid = (N + 3) / 4;     // 25000

    // --- layer 1 aggregation (gemm1 already done in phase A) ---
    agg_kernel<<<aggGrid, 256, 0, stream>>>(bufA, rowptr, cnt, srcIdx, dinv, bufB, N);
    hipMemsetAsync(bnacc, 0, 256 * 4, stream);
    bnstats<<<512, 256, 0, stream>>>(bufB, bnacc, N);
    bnfin<<<1, 128, 0, stream>>>(bnacc, g0, b0, bn_s, bn_t, 1.0f / N);

    // --- layer 2 ---
    gemm_mfma<<<gemmGrid, 256, 0, stream>>>(bufB, Wb1, bn_s, bn_t, bufA, N);
    agg_kernel<<<aggGrid, 256, 0, stream>>>(bufA, rowptr, cnt, srcIdx, dinv, bufB, N);
    hipMemsetAsync(bnacc, 0, 256 * 4, stream);
    bnstats<<<512, 256, 0, stream>>>(bufB, bnacc, N);
    bnfin<<<1, 128, 0, stream>>>(bnacc, g1, b1, bn_s, bn_t, 1.0f / N);

    // --- layer 3 ---
    gemm_mfma<<<gemmGrid, 256, 0, stream>>>(bufB, Wb2, bn_s, bn_t, bufA, N);
    agg_kernel<<<aggGrid, 256, 0, stream>>>(bufA, rowptr, cnt, srcIdx, dinv, bufB, N);

    // --- pool (parallel partials) + head ---
    hipMemsetAsync(poolAcc, 0, 128 * 128 * 4, stream);
    pool_partial<<<N_GRAPHS * POOL_SLICES, 256, 0, stream>>>(bufB, batch, poolAcc, N);
    head_kernel<<<N_GRAPHS, 128, 0, stream>>>(poolAcc, batch, Wg1, bg1, Wg2, bg2, out, N);
}